// Round 4
// baseline (10184.274 us; speedup 1.0000x reference)
//
#include <hip/hip_runtime.h>
#include <hip/hip_bf16.h>
#include <stdint.h>

#define T_STEPS 12
#define NN 20000
#define NE 320000
#define FIN 128
#define HD 256
#define FOUT 128

typedef __attribute__((ext_vector_type(4))) float f32x4;
typedef __attribute__((ext_vector_type(8))) short bf16x8;

static __device__ __forceinline__ float sigmoidf_(float x) {
  return 1.0f / (1.0f + __expf(-x));
}
static __device__ __forceinline__ float b2f(ushort u) {
  union { uint32_t i; float f; } v; v.i = ((uint32_t)u) << 16; return v.f;
}
static __device__ __forceinline__ ushort f2b(float f) {
  __hip_bfloat16 h = __float2bfloat16(f);
  return *reinterpret_cast<ushort*>(&h);
}

// ---------------- CSR build ----------------
__global__ void count_kernel(const int* __restrict__ dst, int* __restrict__ counts) {
  int e = blockIdx.x * blockDim.x + threadIdx.x;
  if (e < NE) atomicAdd(&counts[dst[e]], 1);
}

__global__ void scan_kernel(const int* __restrict__ counts, int* __restrict__ offs,
                            int* __restrict__ cursor) {
  __shared__ int sm[1024];
  __shared__ int carry_s;
  if (threadIdx.x == 0) carry_s = 0;
  __syncthreads();
  const int n = NN;
  int nch = (n + 1023) >> 10;
  for (int c = 0; c < nch; ++c) {
    int i = (c << 10) + (int)threadIdx.x;
    int v = (i < n) ? counts[i] : 0;
    sm[threadIdx.x] = v;
    __syncthreads();
    for (int off = 1; off < 1024; off <<= 1) {
      int t = (threadIdx.x >= (unsigned)off) ? sm[threadIdx.x - off] : 0;
      __syncthreads();
      sm[threadIdx.x] += t;
      __syncthreads();
    }
    int incl = sm[threadIdx.x];
    int carry_local = carry_s;
    if (i < n) {
      int excl = carry_local + incl - v;
      offs[i] = excl;
      cursor[i] = excl;
    }
    __syncthreads();
    if (threadIdx.x == 1023) carry_s = carry_local + incl;
    __syncthreads();
  }
  if (threadIdx.x == 0) offs[n] = carry_s;
}

__global__ void fill_kernel(const int* __restrict__ src, const int* __restrict__ dst,
                            int* __restrict__ cursor, int* __restrict__ esrc) {
  int e = blockIdx.x * blockDim.x + threadIdx.x;
  if (e < NE) {
    int d = dst[e];
    int pos = atomicAdd(&cursor[d], 1);
    esrc[pos] = src[e];
  }
}

// ---------------- aggregation: fp32 gather-sum -> split hi/lo bf16 panels ----------------
// writes hi at [hi1 .. hi1+W), lo at [hi1+lod1 .. ), optional dual destination
template <int W>
__global__ void agg_split(const float* __restrict__ feat, const int* __restrict__ offs,
                          const int* __restrict__ esrc, ushort* __restrict__ out1, int ld1,
                          int hi1, int lod1, ushort* __restrict__ out2, int ld2, int hi2,
                          int lod2) {
  constexpr int PL = W / 64;  // floats per lane (2 or 4)
  int d = blockIdx.x * 4 + (threadIdx.x >> 6);
  int lane = threadIdx.x & 63;
  int beg = offs[d], end = offs[d + 1];
  float acc[PL] = {};
  float acc2[PL] = {};
  int e = beg;
  for (; e + 1 < end; e += 2) {
    const float* r0 = feat + (size_t)esrc[e] * W + lane * PL;
    const float* r1 = feat + (size_t)esrc[e + 1] * W + lane * PL;
    if constexpr (PL == 2) {
      float2 v0 = *reinterpret_cast<const float2*>(r0);
      float2 v1 = *reinterpret_cast<const float2*>(r1);
      acc[0] += v0.x; acc[1] += v0.y;
      acc2[0] += v1.x; acc2[1] += v1.y;
    } else {
      float4 v0 = *reinterpret_cast<const float4*>(r0);
      float4 v1 = *reinterpret_cast<const float4*>(r1);
      acc[0] += v0.x; acc[1] += v0.y; acc[2] += v0.z; acc[3] += v0.w;
      acc2[0] += v1.x; acc2[1] += v1.y; acc2[2] += v1.z; acc2[3] += v1.w;
    }
  }
  if (e < end) {
    const float* r0 = feat + (size_t)esrc[e] * W + lane * PL;
    if constexpr (PL == 2) {
      float2 v0 = *reinterpret_cast<const float2*>(r0);
      acc[0] += v0.x; acc[1] += v0.y;
    } else {
      float4 v0 = *reinterpret_cast<const float4*>(r0);
      acc[0] += v0.x; acc[1] += v0.y; acc[2] += v0.z; acc[3] += v0.w;
    }
  }
  ushort hi[PL], lo[PL];
#pragma unroll
  for (int p = 0; p < PL; ++p) {
    float a = acc[p] + acc2[p];
    hi[p] = f2b(a);
    lo[p] = f2b(a - b2f(hi[p]));
  }
  if constexpr (PL == 2) {
    *reinterpret_cast<ushort2*>(out1 + (size_t)d * ld1 + hi1 + lane * 2) =
        *reinterpret_cast<ushort2*>(hi);
    *reinterpret_cast<ushort2*>(out1 + (size_t)d * ld1 + hi1 + lod1 + lane * 2) =
        *reinterpret_cast<ushort2*>(lo);
    if (out2) {
      *reinterpret_cast<ushort2*>(out2 + (size_t)d * ld2 + hi2 + lane * 2) =
          *reinterpret_cast<ushort2*>(hi);
      *reinterpret_cast<ushort2*>(out2 + (size_t)d * ld2 + hi2 + lod2 + lane * 2) =
          *reinterpret_cast<ushort2*>(lo);
    }
  } else {
    *reinterpret_cast<ushort4*>(out1 + (size_t)d * ld1 + hi1 + lane * 4) =
        *reinterpret_cast<ushort4*>(hi);
    *reinterpret_cast<ushort4*>(out1 + (size_t)d * ld1 + hi1 + lod1 + lane * 4) =
        *reinterpret_cast<ushort4*>(lo);
    if (out2) {
      *reinterpret_cast<ushort4*>(out2 + (size_t)d * ld2 + hi2 + lane * 4) =
          *reinterpret_cast<ushort4*>(hi);
      *reinterpret_cast<ushort4*>(out2 + (size_t)d * ld2 + hi2 + lod2 + lane * 4) =
          *reinterpret_cast<ushort4*>(lo);
    }
  }
}

// ---------------- bf16 MFMA GEMM with A K-wrap ----------------
// C[M][ldc] (fp32) (+)= A' @ B^T + bias, where A' column k maps to
// A column (k >= kwrap ? k - kwrap : k). B is [N][K] bf16.
__global__ __launch_bounds__(256) void gemm_bf16(
    const ushort* __restrict__ A, int lda, int kwrap, const ushort* __restrict__ B, int ldb,
    float* __restrict__ C, int ldc, const float* __restrict__ bias,
    int M, int K, int accumulate) {
  __shared__ ushort As[128 * 64];
  __shared__ ushort Bs[128 * 64];

  int tid = threadIdx.x;
  int wave = tid >> 6;
  int lane = tid & 63;
  int wm = wave >> 1, wn = wave & 1;
  int lrow = lane & 15;
  int kgrp = lane >> 4;

  int m0 = blockIdx.y * 128;
  int n0 = blockIdx.x * 128;

  f32x4 acc[4][4] = {};

  int srow = tid >> 3;       // 0..31
  int skb = (tid & 7) * 16;  // staged byte col

  for (int k0 = 0; k0 < K; k0 += 64) {
    int ka = (k0 >= kwrap) ? k0 - kwrap : k0;
    uint4 av[4], bv[4];
#pragma unroll
    for (int p = 0; p < 4; ++p) {
      int row = p * 32 + srow;
      int gr = m0 + row;
      av[p] = (gr < M)
                  ? *reinterpret_cast<const uint4*>(&A[(size_t)gr * lda + ka + (tid & 7) * 8])
                  : make_uint4(0, 0, 0, 0);
      bv[p] = *reinterpret_cast<const uint4*>(&B[(size_t)(n0 + row) * ldb + k0 + (tid & 7) * 8]);
    }
    __syncthreads();
#pragma unroll
    for (int p = 0; p < 4; ++p) {
      int row = p * 32 + srow;
      int off = row * 128 + (skb ^ ((row & 7) << 4));
      *reinterpret_cast<uint4*>(reinterpret_cast<char*>(As) + off) = av[p];
      *reinterpret_cast<uint4*>(reinterpret_cast<char*>(Bs) + off) = bv[p];
    }
    __syncthreads();

#pragma unroll
    for (int kk = 0; kk < 2; ++kk) {
      bf16x8 af[4], bf[4];
      int kbyte = kk * 64 + kgrp * 16;
#pragma unroll
      for (int i = 0; i < 4; ++i) {
        int ar = wm * 64 + i * 16 + lrow;
        af[i] = *reinterpret_cast<const bf16x8*>(
            reinterpret_cast<const char*>(As) + ar * 128 + (kbyte ^ ((ar & 7) << 4)));
        int br = wn * 64 + i * 16 + lrow;
        bf[i] = *reinterpret_cast<const bf16x8*>(
            reinterpret_cast<const char*>(Bs) + br * 128 + (kbyte ^ ((br & 7) << 4)));
      }
#pragma unroll
      for (int i = 0; i < 4; ++i)
#pragma unroll
        for (int j = 0; j < 4; ++j)
          acc[i][j] = __builtin_amdgcn_mfma_f32_16x16x32_bf16(af[i], bf[j], acc[i][j], 0, 0, 0);
    }
  }

#pragma unroll
  for (int i = 0; i < 4; ++i) {
    int row_base = m0 + wm * 64 + i * 16 + kgrp * 4;
#pragma unroll
    for (int j = 0; j < 4; ++j) {
      int col = n0 + wn * 64 + j * 16 + lrow;
      float bvv = bias ? bias[col] : 0.f;
#pragma unroll
      for (int r = 0; r < 4; ++r) {
        int rg = row_base + r;
        if (rg < M) {
          float v = acc[i][j][r] + bvv;
          float* cp = &C[(size_t)rg * ldc + col];
          if (accumulate) v += *cp;
          *cp = v;
        }
      }
    }
  }
}

// ---------------- GRU elementwise (fp32 state) ----------------
__global__ void eltwise_ru(float* __restrict__ xw, const float* __restrict__ h,
                           float* __restrict__ rh) {
  int idx = blockIdx.x * blockDim.x + threadIdx.x;
  if (idx >= NN * 64) return;
  int nrow = idx >> 6;
  int j4 = (idx & 63) << 2;
  float* p = xw + (size_t)nrow * 768 + j4;
  float4 rpre = *reinterpret_cast<const float4*>(p);
  float4 upre = *reinterpret_cast<const float4*>(p + 256);
  float4 hv = *reinterpret_cast<const float4*>(h + (size_t)nrow * 256 + j4);
  float4 uu, rhv;
  uu.x = sigmoidf_(upre.x); uu.y = sigmoidf_(upre.y);
  uu.z = sigmoidf_(upre.z); uu.w = sigmoidf_(upre.w);
  rhv.x = sigmoidf_(rpre.x) * hv.x;
  rhv.y = sigmoidf_(rpre.y) * hv.y;
  rhv.z = sigmoidf_(rpre.z) * hv.z;
  rhv.w = sigmoidf_(rpre.w) * hv.w;
  *reinterpret_cast<float4*>(p + 256) = uu;
  *reinterpret_cast<float4*>(rh + (size_t)nrow * 256 + j4) = rhv;
}

// h fp32 updated in place; optional hi/lo bf16 panel (ld 512, lo=hi+256)
__global__ void eltwise_c(const float* __restrict__ xw, float* __restrict__ h,
                          ushort* __restrict__ panel) {
  int idx = blockIdx.x * blockDim.x + threadIdx.x;
  if (idx >= NN * 64) return;
  int nrow = idx >> 6;
  int j4 = (idx & 63) << 2;
  float4 cpre = *reinterpret_cast<const float4*>(xw + (size_t)nrow * 768 + 512 + j4);
  float4 uu = *reinterpret_cast<const float4*>(xw + (size_t)nrow * 768 + 256 + j4);
  float* hp = h + (size_t)nrow * 256 + j4;
  float4 hv = *reinterpret_cast<const float4*>(hp);
  float4 nh;
  nh.x = uu.x * hv.x + (1.f - uu.x) * tanhf(cpre.x);
  nh.y = uu.y * hv.y + (1.f - uu.y) * tanhf(cpre.y);
  nh.z = uu.z * hv.z + (1.f - uu.z) * tanhf(cpre.z);
  nh.w = uu.w * hv.w + (1.f - uu.w) * tanhf(cpre.w);
  *reinterpret_cast<float4*>(hp) = nh;
  if (panel) {
    ushort4 hi4, lo4;
    hi4.x = f2b(nh.x); lo4.x = f2b(nh.x - b2f(hi4.x));
    hi4.y = f2b(nh.y); lo4.y = f2b(nh.y - b2f(hi4.y));
    hi4.z = f2b(nh.z); lo4.z = f2b(nh.z - b2f(hi4.z));
    hi4.w = f2b(nh.w); lo4.w = f2b(nh.w - b2f(hi4.w));
    *reinterpret_cast<ushort4*>(panel + (size_t)nrow * 512 + j4) = hi4;
    *reinterpret_cast<ushort4*>(panel + (size_t)nrow * 512 + 256 + j4) = lo4;
  }
}

// ---------------- weight prep ----------------
// mode 0: dst = bf16(W^T); mode 1: dst = bf16(W^T - bf16(W^T))   [dst[n][koff+k]]
__global__ void wtrans(const float* __restrict__ W, ushort* __restrict__ dst,
                       int K, int ldw, int ldd, int koff, int mode) {
  int k = blockIdx.x * blockDim.x + threadIdx.x;
  int n = blockIdx.y;
  if (k < K) {
    float w = W[(size_t)k * ldw + n];
    ushort h = f2b(w);
    dst[(size_t)n * ldd + koff + k] = mode ? f2b(w - b2f(h)) : h;
  }
}

__global__ void bias_comb(const float* __restrict__ bx, const float* __restrict__ bh,
                          float* __restrict__ out) {
  int i = blockIdx.x * blockDim.x + threadIdx.x;
  if (i < 768) out[i] = bx[i] + bh[i];
}

__global__ void copy_kernel(const float* __restrict__ in, float* __restrict__ out, int n4) {
  int i = blockIdx.x * blockDim.x + threadIdx.x;
  if (i < n4) reinterpret_cast<float4*>(out)[i] = reinterpret_cast<const float4*>(in)[i];
}

// ---------------- host ----------------
extern "C" void kernel_launch(void* const* d_in, const int* in_sizes, int n_in,
                              void* d_out, int out_size, void* d_ws, size_t ws_size,
                              hipStream_t stream) {
  const float* x   = (const float*)d_in[0];
  const float* h0  = (const float*)d_in[1];
  const int*   src = (const int*)d_in[2];
  const int*   dst = (const int*)d_in[3];
  const float* Wx0 = (const float*)d_in[4];
  const float* bx0 = (const float*)d_in[5];
  const float* Wh0 = (const float*)d_in[6];
  const float* bh0 = (const float*)d_in[7];
  const float* Wx1 = (const float*)d_in[8];
  const float* bx1 = (const float*)d_in[9];
  const float* Wh1 = (const float*)d_in[10];
  const float* bh1 = (const float*)d_in[11];
  const float* Wo  = (const float*)d_in[12];
  const float* bo  = (const float*)d_in[13];
  float* out = (float*)d_out;

  char* p = (char*)d_ws;
  auto alloc = [&](size_t bytes) {
    char* r = p;
    p += (bytes + 255) & ~(size_t)255;
    return r;
  };
  int* offs   = (int*)alloc((NN + 1) * sizeof(int));
  int* cursor = (int*)alloc(NN * sizeof(int));
  int* counts = (int*)alloc(NN * sizeof(int));
  int* esrc   = (int*)alloc(NE * sizeof(int));
  // B panels: [N rows][K cols] bf16, K = 3 segments (hi | hi | lo)
  ushort* B0  = (ushort*)alloc((size_t)768 * 1152 * 2);
  ushort* B0h = (ushort*)alloc((size_t)256 * 768 * 2);
  ushort* B1  = (ushort*)alloc((size_t)768 * 1536 * 2);
  ushort* B1h = (ushort*)alloc((size_t)256 * 768 * 2);
  ushort* Bo  = (ushort*)alloc((size_t)128 * 768 * 2);
  float* b0c  = (float*)alloc(768 * 4);
  float* b1c  = (float*)alloc(768 * 4);
  // A panels: [hi | lo], GEMM wraps K for seg3
  ushort* A0  = (ushort*)alloc((size_t)NN * 768 * 2);    // [xhi|hhi|xlo|hlo]
  ushort* A1  = (ushort*)alloc((size_t)NN * 1024 * 2);   // [h0hi|h1hi|h0lo|h1lo]
  ushort* RHP = (ushort*)alloc((size_t)NN * 512 * 2);    // [rhhi|rhlo]
  ushort* H1P = (ushort*)alloc((size_t)NN * 512 * 2);    // [h1hi|h1lo]
  float* rhf  = (float*)alloc((size_t)NN * 256 * 4);
  float* xw   = (float*)alloc((size_t)NN * 768 * 4);

  // fp32 GRU states live directly in d_out tail
  float* h0c = out + (size_t)T_STEPS * NN * FOUT;
  float* h1c = h0c + (size_t)NN * HD;

  // CSR
  hipMemsetAsync(counts, 0, NN * sizeof(int), stream);
  count_kernel<<<(NE + 255) / 256, 256, 0, stream>>>(dst, counts);
  scan_kernel<<<1, 1024, 0, stream>>>(counts, offs, cursor);
  fill_kernel<<<(NE + 255) / 256, 256, 0, stream>>>(src, dst, cursor, esrc);

  // weight prep
  hipMemsetAsync(B0, 0, (size_t)768 * 1152 * 2, stream);
  hipMemsetAsync(B1, 0, (size_t)768 * 1536 * 2, stream);
  // B0: K segs at 0 (hi), 384 (hi), 768 (lo); within seg: x@0(128), h@128(256)
  for (int g = 0; g < 3; ++g) {
    const float* W = Wx0 + (size_t)g * 128 * 256;
    ushort* D = B0 + (size_t)g * 256 * 1152;
    wtrans<<<dim3(1, 256), 256, 0, stream>>>(W, D, 128, 256, 1152, 0, 0);
    wtrans<<<dim3(1, 256), 256, 0, stream>>>(W, D, 128, 256, 1152, 384, 0);
    wtrans<<<dim3(1, 256), 256, 0, stream>>>(W, D, 128, 256, 1152, 768, 1);
  }
  for (int g = 0; g < 2; ++g) {
    const float* W = Wh0 + (size_t)g * 256 * 256;
    ushort* D = B0 + (size_t)g * 256 * 1152;
    wtrans<<<dim3(1, 256), 256, 0, stream>>>(W, D, 256, 256, 1152, 128, 0);
    wtrans<<<dim3(1, 256), 256, 0, stream>>>(W, D, 256, 256, 1152, 512, 0);
    wtrans<<<dim3(1, 256), 256, 0, stream>>>(W, D, 256, 256, 1152, 896, 1);
  }
  {
    const float* W = Wh0 + (size_t)2 * 256 * 256;
    wtrans<<<dim3(1, 256), 256, 0, stream>>>(W, B0h, 256, 256, 768, 0, 0);
    wtrans<<<dim3(1, 256), 256, 0, stream>>>(W, B0h, 256, 256, 768, 256, 0);
    wtrans<<<dim3(1, 256), 256, 0, stream>>>(W, B0h, 256, 256, 768, 512, 1);
  }
  // B1: K segs at 0,512 (hi), 1024 (lo); within seg: x@0(256), h@256(256)
  for (int g = 0; g < 3; ++g) {
    const float* W = Wx1 + (size_t)g * 256 * 256;
    ushort* D = B1 + (size_t)g * 256 * 1536;
    wtrans<<<dim3(1, 256), 256, 0, stream>>>(W, D, 256, 256, 1536, 0, 0);
    wtrans<<<dim3(1, 256), 256, 0, stream>>>(W, D, 256, 256, 1536, 512, 0);
    wtrans<<<dim3(1, 256), 256, 0, stream>>>(W, D, 256, 256, 1536, 1024, 1);
  }
  for (int g = 0; g < 2; ++g) {
    const float* W = Wh1 + (size_t)g * 256 * 256;
    ushort* D = B1 + (size_t)g * 256 * 1536;
    wtrans<<<dim3(1, 256), 256, 0, stream>>>(W, D, 256, 256, 1536, 256, 0);
    wtrans<<<dim3(1, 256), 256, 0, stream>>>(W, D, 256, 256, 1536, 768, 0);
    wtrans<<<dim3(1, 256), 256, 0, stream>>>(W, D, 256, 256, 1536, 1280, 1);
  }
  {
    const float* W = Wh1 + (size_t)2 * 256 * 256;
    wtrans<<<dim3(1, 256), 256, 0, stream>>>(W, B1h, 256, 256, 768, 0, 0);
    wtrans<<<dim3(1, 256), 256, 0, stream>>>(W, B1h, 256, 256, 768, 256, 0);
    wtrans<<<dim3(1, 256), 256, 0, stream>>>(W, B1h, 256, 256, 768, 512, 1);
  }
  wtrans<<<dim3(1, 128), 256, 0, stream>>>(Wo, Bo, 256, 128, 768, 0, 0);
  wtrans<<<dim3(1, 128), 256, 0, stream>>>(Wo, Bo, 256, 128, 768, 256, 0);
  wtrans<<<dim3(1, 128), 256, 0, stream>>>(Wo, Bo, 256, 128, 768, 512, 1);
  bias_comb<<<3, 256, 0, stream>>>(bx0, bh0, b0c);
  bias_comb<<<3, 256, 0, stream>>>(bx1, bh1, b1c);

  // init fp32 h states in out tail
  copy_kernel<<<(2 * NN * HD / 4 + 255) / 256, 256, 0, stream>>>(h0, h0c, 2 * NN * HD / 4);

  dim3 blk(256);
  int gy = (NN + 127) / 128;
  int ew_blocks = (NN * 64 + 255) / 256;
  int agg_grid = NN / 4;

  // prime A0's h-part with agg(h0_init) for t=0: hi@128, lo@512 (lod=384)
  agg_split<HD><<<agg_grid, blk, 0, stream>>>(h0c, offs, esrc, A0, 768, 128, 384,
                                              nullptr, 0, 0, 0);

  for (int t = 0; t < T_STEPS; ++t) {
    const float* xt = x + (size_t)t * NN * FIN;

    // ---- layer 0 ----
    agg_split<FIN><<<agg_grid, blk, 0, stream>>>(xt, offs, esrc, A0, 768, 0, 384,
                                                 nullptr, 0, 0, 0);
    gemm_bf16<<<dim3(6, gy), blk, 0, stream>>>(A0, 768, 768, B0, 1152, xw, 768, b0c,
                                               NN, 1152, 0);
    eltwise_ru<<<ew_blocks, blk, 0, stream>>>(xw, h0c, rhf);
    agg_split<HD><<<agg_grid, blk, 0, stream>>>(rhf, offs, esrc, RHP, 512, 0, 256,
                                                nullptr, 0, 0, 0);
    gemm_bf16<<<dim3(2, gy), blk, 0, stream>>>(RHP, 512, 512, B0h, 768, xw + 512, 768,
                                               nullptr, NN, 768, 1);
    eltwise_c<<<ew_blocks, blk, 0, stream>>>(xw, h0c, nullptr);

    // ---- layer 1 ---- (dual-write: A1 h0-part + next step's A0 h-part)
    agg_split<HD><<<agg_grid, blk, 0, stream>>>(h0c, offs, esrc, A1, 1024, 0, 512,
                                                A0, 768, 128, 384);
    agg_split<HD><<<agg_grid, blk, 0, stream>>>(h1c, offs, esrc, A1, 1024, 256, 512,
                                                nullptr, 0, 0, 0);
    gemm_bf16<<<dim3(6, gy), blk, 0, stream>>>(A1, 1024, 1024, B1, 1536, xw, 768, b1c,
                                               NN, 1536, 0);
    eltwise_ru<<<ew_blocks, blk, 0, stream>>>(xw, h1c, rhf);
    agg_split<HD><<<agg_grid, blk, 0, stream>>>(rhf, offs, esrc, RHP, 512, 0, 256,
                                                nullptr, 0, 0, 0);
    gemm_bf16<<<dim3(2, gy), blk, 0, stream>>>(RHP, 512, 512, B1h, 768, xw + 512, 768,
                                               nullptr, NN, 768, 1);
    eltwise_c<<<ew_blocks, blk, 0, stream>>>(xw, h1c, H1P);

    // ---- output projection ----
    gemm_bf16<<<dim3(1, gy), blk, 0, stream>>>(H1P, 512, 512, Bo, 768,
                                               out + (size_t)t * NN * FOUT, 128, bo,
                                               NN, 768, 0);
  }
}

// Round 5
// 8836.324 us; speedup vs baseline: 1.1525x; 1.1525x over previous
//
#include <hip/hip_runtime.h>
#include <hip/hip_bf16.h>
#include <stdint.h>

#define T_STEPS 12
#define NN 20000
#define NE 320000
#define FIN 128
#define HD 256
#define FOUT 128

typedef __attribute__((ext_vector_type(4))) float f32x4;
typedef __attribute__((ext_vector_type(8))) short bf16x8;

static __device__ __forceinline__ float sigmoidf_(float x) {
  return 1.0f / (1.0f + __expf(-x));
}
static __device__ __forceinline__ float b2f(ushort u) {
  union { uint32_t i; float f; } v; v.i = ((uint32_t)u) << 16; return v.f;
}
static __device__ __forceinline__ ushort f2b(float f) {
  __hip_bfloat16 h = __float2bfloat16(f);
  return *reinterpret_cast<ushort*>(&h);
}

// ---------------- CSR build ----------------
__global__ void count_kernel(const int* __restrict__ dst, int* __restrict__ counts) {
  int e = blockIdx.x * blockDim.x + threadIdx.x;
  if (e < NE) atomicAdd(&counts[dst[e]], 1);
}

__global__ void scan_kernel(const int* __restrict__ counts, int* __restrict__ offs,
                            int* __restrict__ cursor) {
  __shared__ int sm[1024];
  __shared__ int carry_s;
  if (threadIdx.x == 0) carry_s = 0;
  __syncthreads();
  const int n = NN;
  int nch = (n + 1023) >> 10;
  for (int c = 0; c < nch; ++c) {
    int i = (c << 10) + (int)threadIdx.x;
    int v = (i < n) ? counts[i] : 0;
    sm[threadIdx.x] = v;
    __syncthreads();
    for (int off = 1; off < 1024; off <<= 1) {
      int t = (threadIdx.x >= (unsigned)off) ? sm[threadIdx.x - off] : 0;
      __syncthreads();
      sm[threadIdx.x] += t;
      __syncthreads();
    }
    int incl = sm[threadIdx.x];
    int carry_local = carry_s;
    if (i < n) {
      int excl = carry_local + incl - v;
      offs[i] = excl;
      cursor[i] = excl;
    }
    __syncthreads();
    if (threadIdx.x == 1023) carry_s = carry_local + incl;
    __syncthreads();
  }
  if (threadIdx.x == 0) offs[n] = carry_s;
}

__global__ void fill_kernel(const int* __restrict__ src, const int* __restrict__ dst,
                            int* __restrict__ cursor, int* __restrict__ esrc) {
  int e = blockIdx.x * blockDim.x + threadIdx.x;
  if (e < NE) {
    int d = dst[e];
    int pos = atomicAdd(&cursor[d], 1);
    esrc[pos] = src[e];
  }
}

// ---------------- aggregation: fp32 gather-sum -> split hi/lo bf16 panels ----------------
template <int W>
__global__ void agg_split(const float* __restrict__ feat, const int* __restrict__ offs,
                          const int* __restrict__ esrc, ushort* __restrict__ out1, int ld1,
                          int hi1, int lod1, ushort* __restrict__ out2, int ld2, int hi2,
                          int lod2) {
  constexpr int PL = W / 64;  // floats per lane (2 or 4)
  int d = blockIdx.x * 4 + (threadIdx.x >> 6);
  int lane = threadIdx.x & 63;
  int beg = offs[d], end = offs[d + 1];
  float acc[PL] = {};
  float acc2[PL] = {};
  int e = beg;
  for (; e + 1 < end; e += 2) {
    const float* r0 = feat + (size_t)esrc[e] * W + lane * PL;
    const float* r1 = feat + (size_t)esrc[e + 1] * W + lane * PL;
    if constexpr (PL == 2) {
      float2 v0 = *reinterpret_cast<const float2*>(r0);
      float2 v1 = *reinterpret_cast<const float2*>(r1);
      acc[0] += v0.x; acc[1] += v0.y;
      acc2[0] += v1.x; acc2[1] += v1.y;
    } else {
      float4 v0 = *reinterpret_cast<const float4*>(r0);
      float4 v1 = *reinterpret_cast<const float4*>(r1);
      acc[0] += v0.x; acc[1] += v0.y; acc[2] += v0.z; acc[3] += v0.w;
      acc2[0] += v1.x; acc2[1] += v1.y; acc2[2] += v1.z; acc2[3] += v1.w;
    }
  }
  if (e < end) {
    const float* r0 = feat + (size_t)esrc[e] * W + lane * PL;
    if constexpr (PL == 2) {
      float2 v0 = *reinterpret_cast<const float2*>(r0);
      acc[0] += v0.x; acc[1] += v0.y;
    } else {
      float4 v0 = *reinterpret_cast<const float4*>(r0);
      acc[0] += v0.x; acc[1] += v0.y; acc[2] += v0.z; acc[3] += v0.w;
    }
  }
  ushort hi[PL], lo[PL];
#pragma unroll
  for (int p = 0; p < PL; ++p) {
    float a = acc[p] + acc2[p];
    hi[p] = f2b(a);
    lo[p] = f2b(a - b2f(hi[p]));
  }
  if constexpr (PL == 2) {
    *reinterpret_cast<ushort2*>(out1 + (size_t)d * ld1 + hi1 + lane * 2) =
        *reinterpret_cast<ushort2*>(hi);
    *reinterpret_cast<ushort2*>(out1 + (size_t)d * ld1 + hi1 + lod1 + lane * 2) =
        *reinterpret_cast<ushort2*>(lo);
    if (out2) {
      *reinterpret_cast<ushort2*>(out2 + (size_t)d * ld2 + hi2 + lane * 2) =
          *reinterpret_cast<ushort2*>(hi);
      *reinterpret_cast<ushort2*>(out2 + (size_t)d * ld2 + hi2 + lod2 + lane * 2) =
          *reinterpret_cast<ushort2*>(lo);
    }
  } else {
    *reinterpret_cast<ushort4*>(out1 + (size_t)d * ld1 + hi1 + lane * 4) =
        *reinterpret_cast<ushort4*>(hi);
    *reinterpret_cast<ushort4*>(out1 + (size_t)d * ld1 + hi1 + lod1 + lane * 4) =
        *reinterpret_cast<ushort4*>(lo);
    if (out2) {
      *reinterpret_cast<ushort4*>(out2 + (size_t)d * ld2 + hi2 + lane * 4) =
          *reinterpret_cast<ushort4*>(hi);
      *reinterpret_cast<ushort4*>(out2 + (size_t)d * ld2 + hi2 + lod2 + lane * 4) =
          *reinterpret_cast<ushort4*>(lo);
    }
  }
}

// ---------------- bf16 MFMA GEMM with A K-wrap + XCD-local grid remap ----------------
// C[M][ldc] (fp32) (+)= A' @ B^T + bias; A' col k maps to A col (k>=kwrap ? k-kwrap : k)
// Flat grid of 8*rpg*nch blocks: xcd = p&7 owns rows [xcd*rpg, (xcd+1)*rpg), all nch
// col-chunks of a row adjacent in dispatch order -> A row-tile read once per XCD L2.
__global__ __launch_bounds__(256) void gemm_bf16(
    const ushort* __restrict__ A, int lda, int kwrap, const ushort* __restrict__ B, int ldb,
    float* __restrict__ C, int ldc, const float* __restrict__ bias,
    int M, int K, int accumulate, int nch, int rpg) {
  __shared__ ushort As[128 * 64];
  __shared__ ushort Bs[128 * 64];

  int p = blockIdx.x;
  int xcd = p & 7;
  int q = p >> 3;
  int rowt = xcd * rpg + q / nch;
  int chunk = q % nch;
  int m0 = rowt * 128;
  if (m0 >= M) return;
  int n0 = chunk * 128;

  int tid = threadIdx.x;
  int wave = tid >> 6;
  int lane = tid & 63;
  int wm = wave >> 1, wn = wave & 1;
  int lrow = lane & 15;
  int kgrp = lane >> 4;

  f32x4 acc[4][4] = {};

  int srow = tid >> 3;       // 0..31
  int skb = (tid & 7) * 16;  // staged byte col

  for (int k0 = 0; k0 < K; k0 += 64) {
    int ka = (k0 >= kwrap) ? k0 - kwrap : k0;
    uint4 av[4], bv[4];
#pragma unroll
    for (int p4 = 0; p4 < 4; ++p4) {
      int row = p4 * 32 + srow;
      int gr = m0 + row;
      av[p4] = (gr < M)
                   ? *reinterpret_cast<const uint4*>(&A[(size_t)gr * lda + ka + (tid & 7) * 8])
                   : make_uint4(0, 0, 0, 0);
      bv[p4] = *reinterpret_cast<const uint4*>(&B[(size_t)(n0 + row) * ldb + k0 + (tid & 7) * 8]);
    }
    __syncthreads();
#pragma unroll
    for (int p4 = 0; p4 < 4; ++p4) {
      int row = p4 * 32 + srow;
      int off = row * 128 + (skb ^ ((row & 7) << 4));
      *reinterpret_cast<uint4*>(reinterpret_cast<char*>(As) + off) = av[p4];
      *reinterpret_cast<uint4*>(reinterpret_cast<char*>(Bs) + off) = bv[p4];
    }
    __syncthreads();

#pragma unroll
    for (int kk = 0; kk < 2; ++kk) {
      bf16x8 af[4], bf[4];
      int kbyte = kk * 64 + kgrp * 16;
#pragma unroll
      for (int i = 0; i < 4; ++i) {
        int ar = wm * 64 + i * 16 + lrow;
        af[i] = *reinterpret_cast<const bf16x8*>(
            reinterpret_cast<const char*>(As) + ar * 128 + (kbyte ^ ((ar & 7) << 4)));
        int br = wn * 64 + i * 16 + lrow;
        bf[i] = *reinterpret_cast<const bf16x8*>(
            reinterpret_cast<const char*>(Bs) + br * 128 + (kbyte ^ ((br & 7) << 4)));
      }
      // operand-swapped: D[n][m] -> lane's 4 regs = 4 consecutive output COLUMNS
#pragma unroll
      for (int i = 0; i < 4; ++i)
#pragma unroll
        for (int j = 0; j < 4; ++j)
          acc[i][j] = __builtin_amdgcn_mfma_f32_16x16x32_bf16(bf[j], af[i], acc[i][j], 0, 0, 0);
    }
  }

  // epilogue: acc[i][j][r] = C[m0+wm*64+i*16+lrow][n0+wn*64+j*16+kgrp*4+r]
#pragma unroll
  for (int i = 0; i < 4; ++i) {
    int m = m0 + wm * 64 + i * 16 + lrow;
    if (m >= M) continue;
#pragma unroll
    for (int j = 0; j < 4; ++j) {
      int colbase = n0 + wn * 64 + j * 16 + kgrp * 4;
      f32x4 v = acc[i][j];
      if (bias) {
        float4 bv4 = *reinterpret_cast<const float4*>(&bias[colbase]);
        v[0] += bv4.x; v[1] += bv4.y; v[2] += bv4.z; v[3] += bv4.w;
      }
      float* cp = &C[(size_t)m * ldc + colbase];
      if (accumulate) {
        float4 o = *reinterpret_cast<const float4*>(cp);
        v[0] += o.x; v[1] += o.y; v[2] += o.z; v[3] += o.w;
      }
      *reinterpret_cast<f32x4*>(cp) = v;
    }
  }
}

// ---------------- GRU elementwise (fp32 state) ----------------
__global__ void eltwise_ru(float* __restrict__ xw, const float* __restrict__ h,
                           float* __restrict__ rh) {
  int idx = blockIdx.x * blockDim.x + threadIdx.x;
  if (idx >= NN * 64) return;
  int nrow = idx >> 6;
  int j4 = (idx & 63) << 2;
  float* p = xw + (size_t)nrow * 768 + j4;
  float4 rpre = *reinterpret_cast<const float4*>(p);
  float4 upre = *reinterpret_cast<const float4*>(p + 256);
  float4 hv = *reinterpret_cast<const float4*>(h + (size_t)nrow * 256 + j4);
  float4 uu, rhv;
  uu.x = sigmoidf_(upre.x); uu.y = sigmoidf_(upre.y);
  uu.z = sigmoidf_(upre.z); uu.w = sigmoidf_(upre.w);
  rhv.x = sigmoidf_(rpre.x) * hv.x;
  rhv.y = sigmoidf_(rpre.y) * hv.y;
  rhv.z = sigmoidf_(rpre.z) * hv.z;
  rhv.w = sigmoidf_(rpre.w) * hv.w;
  *reinterpret_cast<float4*>(p + 256) = uu;
  *reinterpret_cast<float4*>(rh + (size_t)nrow * 256 + j4) = rhv;
}

// h fp32 updated in place; optional hi/lo bf16 panel (ld 512, lo=hi+256)
__global__ void eltwise_c(const float* __restrict__ xw, float* __restrict__ h,
                          ushort* __restrict__ panel) {
  int idx = blockIdx.x * blockDim.x + threadIdx.x;
  if (idx >= NN * 64) return;
  int nrow = idx >> 6;
  int j4 = (idx & 63) << 2;
  float4 cpre = *reinterpret_cast<const float4*>(xw + (size_t)nrow * 768 + 512 + j4);
  float4 uu = *reinterpret_cast<const float4*>(xw + (size_t)nrow * 768 + 256 + j4);
  float* hp = h + (size_t)nrow * 256 + j4;
  float4 hv = *reinterpret_cast<const float4*>(hp);
  float4 nh;
  nh.x = uu.x * hv.x + (1.f - uu.x) * tanhf(cpre.x);
  nh.y = uu.y * hv.y + (1.f - uu.y) * tanhf(cpre.y);
  nh.z = uu.z * hv.z + (1.f - uu.z) * tanhf(cpre.z);
  nh.w = uu.w * hv.w + (1.f - uu.w) * tanhf(cpre.w);
  *reinterpret_cast<float4*>(hp) = nh;
  if (panel) {
    ushort4 hi4, lo4;
    hi4.x = f2b(nh.x); lo4.x = f2b(nh.x - b2f(hi4.x));
    hi4.y = f2b(nh.y); lo4.y = f2b(nh.y - b2f(hi4.y));
    hi4.z = f2b(nh.z); lo4.z = f2b(nh.z - b2f(hi4.z));
    hi4.w = f2b(nh.w); lo4.w = f2b(nh.w - b2f(hi4.w));
    *reinterpret_cast<ushort4*>(panel + (size_t)nrow * 512 + j4) = hi4;
    *reinterpret_cast<ushort4*>(panel + (size_t)nrow * 512 + 256 + j4) = lo4;
  }
}

// ---------------- weight prep ----------------
// mode 0: dst = bf16(W^T); mode 1: dst = bf16(W^T - bf16(W^T))   [dst[n][koff+k]]
__global__ void wtrans(const float* __restrict__ W, ushort* __restrict__ dst,
                       int K, int ldw, int ldd, int koff, int mode) {
  int k = blockIdx.x * blockDim.x + threadIdx.x;
  int n = blockIdx.y;
  if (k < K) {
    float w = W[(size_t)k * ldw + n];
    ushort h = f2b(w);
    dst[(size_t)n * ldd + koff + k] = mode ? f2b(w - b2f(h)) : h;
  }
}

__global__ void bias_comb(const float* __restrict__ bx, const float* __restrict__ bh,
                          float* __restrict__ out) {
  int i = blockIdx.x * blockDim.x + threadIdx.x;
  if (i < 768) out[i] = bx[i] + bh[i];
}

__global__ void copy_kernel(const float* __restrict__ in, float* __restrict__ out, int n4) {
  int i = blockIdx.x * blockDim.x + threadIdx.x;
  if (i < n4) reinterpret_cast<float4*>(out)[i] = reinterpret_cast<const float4*>(in)[i];
}

// ---------------- host ----------------
extern "C" void kernel_launch(void* const* d_in, const int* in_sizes, int n_in,
                              void* d_out, int out_size, void* d_ws, size_t ws_size,
                              hipStream_t stream) {
  const float* x   = (const float*)d_in[0];
  const float* h0  = (const float*)d_in[1];
  const int*   src = (const int*)d_in[2];
  const int*   dst = (const int*)d_in[3];
  const float* Wx0 = (const float*)d_in[4];
  const float* bx0 = (const float*)d_in[5];
  const float* Wh0 = (const float*)d_in[6];
  const float* bh0 = (const float*)d_in[7];
  const float* Wx1 = (const float*)d_in[8];
  const float* bx1 = (const float*)d_in[9];
  const float* Wh1 = (const float*)d_in[10];
  const float* bh1 = (const float*)d_in[11];
  const float* Wo  = (const float*)d_in[12];
  const float* bo  = (const float*)d_in[13];
  float* out = (float*)d_out;

  char* p = (char*)d_ws;
  auto alloc = [&](size_t bytes) {
    char* r = p;
    p += (bytes + 255) & ~(size_t)255;
    return r;
  };
  int* offs   = (int*)alloc((NN + 1) * sizeof(int));
  int* cursor = (int*)alloc(NN * sizeof(int));
  int* counts = (int*)alloc(NN * sizeof(int));
  int* esrc   = (int*)alloc(NE * sizeof(int));
  // B panels: [N rows][K cols] bf16, K = 3 segments (hi | hi | lo)
  ushort* B0  = (ushort*)alloc((size_t)768 * 1152 * 2);
  ushort* B0h = (ushort*)alloc((size_t)256 * 768 * 2);
  ushort* B1  = (ushort*)alloc((size_t)768 * 1536 * 2);
  ushort* B1h = (ushort*)alloc((size_t)256 * 768 * 2);
  ushort* Bo  = (ushort*)alloc((size_t)128 * 768 * 2);
  float* b0c  = (float*)alloc(768 * 4);
  float* b1c  = (float*)alloc(768 * 4);
  // A panels: [hi | lo], GEMM wraps K for seg3
  ushort* A0  = (ushort*)alloc((size_t)NN * 768 * 2);    // [xhi|hhi|xlo|hlo]
  ushort* A1  = (ushort*)alloc((size_t)NN * 1024 * 2);   // [h0hi|h1hi|h0lo|h1lo]
  ushort* RHP = (ushort*)alloc((size_t)NN * 512 * 2);    // [rhhi|rhlo]
  ushort* H1P = (ushort*)alloc((size_t)NN * 512 * 2);    // [h1hi|h1lo]
  float* rhf  = (float*)alloc((size_t)NN * 256 * 4);
  float* xw   = (float*)alloc((size_t)NN * 768 * 4);

  // fp32 GRU states live directly in d_out tail
  float* h0c = out + (size_t)T_STEPS * NN * FOUT;
  float* h1c = h0c + (size_t)NN * HD;

  // CSR
  hipMemsetAsync(counts, 0, NN * sizeof(int), stream);
  count_kernel<<<(NE + 255) / 256, 256, 0, stream>>>(dst, counts);
  scan_kernel<<<1, 1024, 0, stream>>>(counts, offs, cursor);
  fill_kernel<<<(NE + 255) / 256, 256, 0, stream>>>(src, dst, cursor, esrc);

  // weight prep
  hipMemsetAsync(B0, 0, (size_t)768 * 1152 * 2, stream);
  hipMemsetAsync(B1, 0, (size_t)768 * 1536 * 2, stream);
  // B0: K segs at 0 (hi), 384 (hi), 768 (lo); within seg: x@0(128), h@128(256)
  for (int g = 0; g < 3; ++g) {
    const float* W = Wx0 + (size_t)g * 128 * 256;
    ushort* D = B0 + (size_t)g * 256 * 1152;
    wtrans<<<dim3(1, 256), 256, 0, stream>>>(W, D, 128, 256, 1152, 0, 0);
    wtrans<<<dim3(1, 256), 256, 0, stream>>>(W, D, 128, 256, 1152, 384, 0);
    wtrans<<<dim3(1, 256), 256, 0, stream>>>(W, D, 128, 256, 1152, 768, 1);
  }
  for (int g = 0; g < 2; ++g) {
    const float* W = Wh0 + (size_t)g * 256 * 256;
    ushort* D = B0 + (size_t)g * 256 * 1152;
    wtrans<<<dim3(1, 256), 256, 0, stream>>>(W, D, 256, 256, 1152, 128, 0);
    wtrans<<<dim3(1, 256), 256, 0, stream>>>(W, D, 256, 256, 1152, 512, 0);
    wtrans<<<dim3(1, 256), 256, 0, stream>>>(W, D, 256, 256, 1152, 896, 1);
  }
  {
    const float* W = Wh0 + (size_t)2 * 256 * 256;
    wtrans<<<dim3(1, 256), 256, 0, stream>>>(W, B0h, 256, 256, 768, 0, 0);
    wtrans<<<dim3(1, 256), 256, 0, stream>>>(W, B0h, 256, 256, 768, 256, 0);
    wtrans<<<dim3(1, 256), 256, 0, stream>>>(W, B0h, 256, 256, 768, 512, 1);
  }
  // B1: K segs at 0,512 (hi), 1024 (lo); within seg: x@0(256), h@256(256)
  for (int g = 0; g < 3; ++g) {
    const float* W = Wx1 + (size_t)g * 256 * 256;
    ushort* D = B1 + (size_t)g * 256 * 1536;
    wtrans<<<dim3(1, 256), 256, 0, stream>>>(W, D, 256, 256, 1536, 0, 0);
    wtrans<<<dim3(1, 256), 256, 0, stream>>>(W, D, 256, 256, 1536, 512, 0);
    wtrans<<<dim3(1, 256), 256, 0, stream>>>(W, D, 256, 256, 1536, 1024, 1);
  }
  for (int g = 0; g < 2; ++g) {
    const float* W = Wh1 + (size_t)g * 256 * 256;
    ushort* D = B1 + (size_t)g * 256 * 1536;
    wtrans<<<dim3(1, 256), 256, 0, stream>>>(W, D, 256, 256, 1536, 256, 0);
    wtrans<<<dim3(1, 256), 256, 0, stream>>>(W, D, 256, 256, 1536, 768, 0);
    wtrans<<<dim3(1, 256), 256, 0, stream>>>(W, D, 256, 256, 1536, 1280, 1);
  }
  {
    const float* W = Wh1 + (size_t)2 * 256 * 256;
    wtrans<<<dim3(1, 256), 256, 0, stream>>>(W, B1h, 256, 256, 768, 0, 0);
    wtrans<<<dim3(1, 256), 256, 0, stream>>>(W, B1h, 256, 256, 768, 256, 0);
    wtrans<<<dim3(1, 256), 256, 0, stream>>>(W, B1h, 256, 256, 768, 512, 1);
  }
  wtrans<<<dim3(1, 128), 256, 0, stream>>>(Wo, Bo, 256, 128, 768, 0, 0);
  wtrans<<<dim3(1, 128), 256, 0, stream>>>(Wo, Bo, 256, 128, 768, 256, 0);
  wtrans<<<dim3(1, 128), 256, 0, stream>>>(Wo, Bo, 256, 128, 768, 512, 1);
  bias_comb<<<3, 256, 0, stream>>>(bx0, bh0, b0c);
  bias_comb<<<3, 256, 0, stream>>>(bx1, bh1, b1c);

  // init fp32 h states in out tail
  copy_kernel<<<(2 * NN * HD / 4 + 255) / 256, 256, 0, stream>>>(h0, h0c, 2 * NN * HD / 4);

  dim3 blk(256);
  const int RPG = 20;  // ceil(157 row-tiles / 8 XCDs)
  int g6 = 8 * RPG * 6, g2 = 8 * RPG * 2, g1 = 8 * RPG * 1;
  int ew_blocks = (NN * 64 + 255) / 256;
  int agg_grid = NN / 4;

  // prime A0's h-part with agg(h0_init) for t=0: hi@128, lo@512 (lod=384)
  agg_split<HD><<<agg_grid, blk, 0, stream>>>(h0c, offs, esrc, A0, 768, 128, 384,
                                              nullptr, 0, 0, 0);

  for (int t = 0; t < T_STEPS; ++t) {
    const float* xt = x + (size_t)t * NN * FIN;

    // ---- layer 0 ----
    agg_split<FIN><<<agg_grid, blk, 0, stream>>>(xt, offs, esrc, A0, 768, 0, 384,
                                                 nullptr, 0, 0, 0);
    gemm_bf16<<<g6, blk, 0, stream>>>(A0, 768, 768, B0, 1152, xw, 768, b0c,
                                      NN, 1152, 0, 6, RPG);
    eltwise_ru<<<ew_blocks, blk, 0, stream>>>(xw, h0c, rhf);
    agg_split<HD><<<agg_grid, blk, 0, stream>>>(rhf, offs, esrc, RHP, 512, 0, 256,
                                                nullptr, 0, 0, 0);
    gemm_bf16<<<g2, blk, 0, stream>>>(RHP, 512, 512, B0h, 768, xw + 512, 768,
                                      nullptr, NN, 768, 1, 2, RPG);
    eltwise_c<<<ew_blocks, blk, 0, stream>>>(xw, h0c, nullptr);

    // ---- layer 1 ---- (dual-write: A1 h0-part + next step's A0 h-part)
    agg_split<HD><<<agg_grid, blk, 0, stream>>>(h0c, offs, esrc, A1, 1024, 0, 512,
                                                A0, 768, 128, 384);
    agg_split<HD><<<agg_grid, blk, 0, stream>>>(h1c, offs, esrc, A1, 1024, 256, 512,
                                                nullptr, 0, 0, 0);
    gemm_bf16<<<g6, blk, 0, stream>>>(A1, 1024, 1024, B1, 1536, xw, 768, b1c,
                                      NN, 1536, 0, 6, RPG);
    eltwise_ru<<<ew_blocks, blk, 0, stream>>>(xw, h1c, rhf);
    agg_split<HD><<<agg_grid, blk, 0, stream>>>(rhf, offs, esrc, RHP, 512, 0, 256,
                                                nullptr, 0, 0, 0);
    gemm_bf16<<<g2, blk, 0, stream>>>(RHP, 512, 512, B1h, 768, xw + 512, 768,
                                      nullptr, NN, 768, 1, 2, RPG);
    eltwise_c<<<ew_blocks, blk, 0, stream>>>(xw, h1c, H1P);

    // ---- output projection ----
    gemm_bf16<<<g1, blk, 0, stream>>>(H1P, 512, 512, Bo, 768,
                                      out + (size_t)t * NN * FOUT, 128, bo,
                                      NN, 768, 0, 1, RPG);
  }
}

// Round 8
// 7037.358 us; speedup vs baseline: 1.4472x; 1.2556x over previous
//
#include <hip/hip_runtime.h>
#include <hip/hip_bf16.h>
#include <stdint.h>

#define T_STEPS 12
#define NN 20000
#define NE 320000
#define FIN 128
#define HD 256
#define FOUT 128

typedef __attribute__((ext_vector_type(4))) float f32x4;
typedef __attribute__((ext_vector_type(8))) _Float16 f16x8;

static __device__ __forceinline__ float sigmoidf_(float x) {
  return 1.0f / (1.0f + __expf(-x));
}
static __device__ __forceinline__ ushort f2h(float f) {
  union { ushort s; _Float16 h; } v; v.h = (_Float16)f; return v.s;
}
static __device__ __forceinline__ float h2f_(_Float16 h) { return (float)h; }

// ---------------- CSR build ----------------
__global__ void count_kernel(const int* __restrict__ dst, int* __restrict__ counts) {
  int e = blockIdx.x * blockDim.x + threadIdx.x;
  if (e < NE) atomicAdd(&counts[dst[e]], 1);
}

__global__ void scan_kernel(const int* __restrict__ counts, int* __restrict__ offs,
                            int* __restrict__ cursor) {
  __shared__ int sm[1024];
  __shared__ int carry_s;
  if (threadIdx.x == 0) carry_s = 0;
  __syncthreads();
  const int n = NN;
  int nch = (n + 1023) >> 10;
  for (int c = 0; c < nch; ++c) {
    int i = (c << 10) + (int)threadIdx.x;
    int v = (i < n) ? counts[i] : 0;
    sm[threadIdx.x] = v;
    __syncthreads();
    for (int off = 1; off < 1024; off <<= 1) {
      int t = (threadIdx.x >= (unsigned)off) ? sm[threadIdx.x - off] : 0;
      __syncthreads();
      sm[threadIdx.x] += t;
      __syncthreads();
    }
    int incl = sm[threadIdx.x];
    int carry_local = carry_s;
    if (i < n) {
      int excl = carry_local + incl - v;
      offs[i] = excl;
      cursor[i] = excl;
    }
    __syncthreads();
    if (threadIdx.x == 1023) carry_s = carry_local + incl;
    __syncthreads();
  }
  if (threadIdx.x == 0) offs[n] = carry_s;
}

__global__ void fill_kernel(const int* __restrict__ src, const int* __restrict__ dst,
                            int* __restrict__ cursor, int* __restrict__ esrc) {
  int e = blockIdx.x * blockDim.x + threadIdx.x;
  if (e < NE) {
    int d = dst[e];
    int pos = atomicAdd(&cursor[d], 1);
    esrc[pos] = src[e];
  }
}

// ---------------- aggregation: fp32 gather-sum -> fp16 hi/lo split output ----------------
// out row (stride ld): hi at [0..W), lo at [W..2W)
template <int W>
__global__ void agg_split(const float* __restrict__ feat, const int* __restrict__ offs,
                          const int* __restrict__ esrc, _Float16* __restrict__ out, int ld) {
  constexpr int PL = W / 64;  // floats per lane (2 or 4)
  int d = blockIdx.x * 4 + (threadIdx.x >> 6);
  int lane = threadIdx.x & 63;
  int beg = offs[d], end = offs[d + 1];
  float acc[PL] = {};
  float acc2[PL] = {};
  int e = beg;
  for (; e + 1 < end; e += 2) {
    const float* r0 = feat + (size_t)esrc[e] * W + lane * PL;
    const float* r1 = feat + (size_t)esrc[e + 1] * W + lane * PL;
    if constexpr (PL == 2) {
      float2 v0 = *reinterpret_cast<const float2*>(r0);
      float2 v1 = *reinterpret_cast<const float2*>(r1);
      acc[0] += v0.x; acc[1] += v0.y;
      acc2[0] += v1.x; acc2[1] += v1.y;
    } else {
      float4 v0 = *reinterpret_cast<const float4*>(r0);
      float4 v1 = *reinterpret_cast<const float4*>(r1);
      acc[0] += v0.x; acc[1] += v0.y; acc[2] += v0.z; acc[3] += v0.w;
      acc2[0] += v1.x; acc2[1] += v1.y; acc2[2] += v1.z; acc2[3] += v1.w;
    }
  }
  if (e < end) {
    const float* r0 = feat + (size_t)esrc[e] * W + lane * PL;
    if constexpr (PL == 2) {
      float2 v0 = *reinterpret_cast<const float2*>(r0);
      acc[0] += v0.x; acc[1] += v0.y;
    } else {
      float4 v0 = *reinterpret_cast<const float4*>(r0);
      acc[0] += v0.x; acc[1] += v0.y; acc[2] += v0.z; acc[3] += v0.w;
    }
  }
  ushort hi[PL], lo[PL];
#pragma unroll
  for (int p = 0; p < PL; ++p) {
    float a = acc[p] + acc2[p];
    hi[p] = f2h(a);
    union { ushort s; _Float16 h; } u; u.s = hi[p];
    lo[p] = f2h(a - (float)u.h);
  }
  if constexpr (PL == 2) {
    *reinterpret_cast<ushort2*>(out + (size_t)d * ld + lane * 2) = *reinterpret_cast<ushort2*>(hi);
    *reinterpret_cast<ushort2*>(out + (size_t)d * ld + W + lane * 2) = *reinterpret_cast<ushort2*>(lo);
  } else {
    *reinterpret_cast<ushort4*>(out + (size_t)d * ld + lane * 4) = *reinterpret_cast<ushort4*>(hi);
    *reinterpret_cast<ushort4*>(out + (size_t)d * ld + W + lane * 4) = *reinterpret_cast<ushort4*>(lo);
  }
}

// batched x-aggregation over all T steps: grid (NN/4, T); out [t][N][256] = [hi128|lo128]
__global__ void agg_split_x(const float* __restrict__ x, const int* __restrict__ offs,
                            const int* __restrict__ esrc, _Float16* __restrict__ out) {
  int t = blockIdx.y;
  const float* feat = x + (size_t)t * NN * FIN;
  _Float16* o = out + (size_t)t * NN * 256;
  int d = blockIdx.x * 4 + (threadIdx.x >> 6);
  int lane = threadIdx.x & 63;
  int beg = offs[d], end = offs[d + 1];
  float a0 = 0, a1 = 0, c0 = 0, c1 = 0;
  int e = beg;
  for (; e + 1 < end; e += 2) {
    float2 v0 = *reinterpret_cast<const float2*>(feat + (size_t)esrc[e] * FIN + lane * 2);
    float2 v1 = *reinterpret_cast<const float2*>(feat + (size_t)esrc[e + 1] * FIN + lane * 2);
    a0 += v0.x; a1 += v0.y;
    c0 += v1.x; c1 += v1.y;
  }
  if (e < end) {
    float2 v0 = *reinterpret_cast<const float2*>(feat + (size_t)esrc[e] * FIN + lane * 2);
    a0 += v0.x; a1 += v0.y;
  }
  float s0 = a0 + c0, s1 = a1 + c1;
  ushort2 hi, lo;
  hi.x = f2h(s0); hi.y = f2h(s1);
  union { ushort s; _Float16 h; } u0, u1;
  u0.s = hi.x; u1.s = hi.y;
  lo.x = f2h(s0 - (float)u0.h); lo.y = f2h(s1 - (float)u1.h);
  *reinterpret_cast<ushort2*>(o + (size_t)d * 256 + lane * 2) = hi;
  *reinterpret_cast<ushort2*>(o + (size_t)d * 256 + FIN + lane * 2) = lo;
}

// ---------------- fp16 MFMA GEMM, two A-sources split at ksplit ----------------
// C[M][ldc] (fp32) (+)= [Aa | Ab] @ B^T + bias; col k < ksplit from Aa, else Ab.
// XCD-local flat grid: xcd = p&7 owns contiguous row-tile band, col-chunks adjacent.
__global__ __launch_bounds__(256) void gemm_f16(
    const _Float16* __restrict__ Aa, int lda_a, int ksplit,
    const _Float16* __restrict__ Ab, int lda_b,
    const _Float16* __restrict__ B, int ldb,
    float* __restrict__ C, int ldc, const float* __restrict__ bias,
    int M, int K, int accumulate, int nch, int rpg) {
  __shared__ _Float16 As[128 * 64];
  __shared__ _Float16 Bs[128 * 64];

  int p = blockIdx.x;
  int xcd = p & 7;
  int q = p >> 3;
  int rowt = xcd * rpg + q / nch;
  int chunk = q % nch;
  int m0 = rowt * 128;
  if (m0 >= M) return;
  int n0 = chunk * 128;

  int tid = threadIdx.x;
  int wave = tid >> 6;
  int lane = tid & 63;
  int wm = wave >> 1, wn = wave & 1;
  int lrow = lane & 15;
  int kgrp = lane >> 4;

  f32x4 acc[4][4] = {};

  int srow = tid >> 3;       // 0..31
  int skb = (tid & 7) * 16;  // staged byte col

  for (int k0 = 0; k0 < K; k0 += 64) {
    const _Float16* Abase;
    int kk0, ldA;
    if (k0 < ksplit) { Abase = Aa; kk0 = k0; ldA = lda_a; }
    else             { Abase = Ab; kk0 = k0 - ksplit; ldA = lda_b; }
    uint4 av[4], bv[4];
#pragma unroll
    for (int p4 = 0; p4 < 4; ++p4) {
      int row = p4 * 32 + srow;
      int gr = m0 + row;
      av[p4] = (gr < M)
                   ? *reinterpret_cast<const uint4*>(&Abase[(size_t)gr * ldA + kk0 + (tid & 7) * 8])
                   : make_uint4(0, 0, 0, 0);
      bv[p4] = *reinterpret_cast<const uint4*>(&B[(size_t)(n0 + row) * ldb + k0 + (tid & 7) * 8]);
    }
    __syncthreads();
#pragma unroll
    for (int p4 = 0; p4 < 4; ++p4) {
      int row = p4 * 32 + srow;
      int off = row * 128 + (skb ^ ((row & 7) << 4));
      *reinterpret_cast<uint4*>(reinterpret_cast<char*>(As) + off) = av[p4];
      *reinterpret_cast<uint4*>(reinterpret_cast<char*>(Bs) + off) = bv[p4];
    }
    __syncthreads();

#pragma unroll
    for (int kk = 0; kk < 2; ++kk) {
      f16x8 af[4], bf[4];
      int kbyte = kk * 64 + kgrp * 16;
#pragma unroll
      for (int i = 0; i < 4; ++i) {
        int ar = wm * 64 + i * 16 + lrow;
        af[i] = *reinterpret_cast<const f16x8*>(
            reinterpret_cast<const char*>(As) + ar * 128 + (kbyte ^ ((ar & 7) << 4)));
        int br = wn * 64 + i * 16 + lrow;
        bf[i] = *reinterpret_cast<const f16x8*>(
            reinterpret_cast<const char*>(Bs) + br * 128 + (kbyte ^ ((br & 7) << 4)));
      }
      // operand-swapped: lane's 4 acc regs = 4 consecutive output COLUMNS
#pragma unroll
      for (int i = 0; i < 4; ++i)
#pragma unroll
        for (int j = 0; j < 4; ++j)
          acc[i][j] = __builtin_amdgcn_mfma_f32_16x16x32_f16(bf[j], af[i], acc[i][j], 0, 0, 0);
    }
  }

  // epilogue: acc[i][j][r] = C[m0+wm*64+i*16+lrow][n0+wn*64+j*16+kgrp*4+r]
#pragma unroll
  for (int i = 0; i < 4; ++i) {
    int m = m0 + wm * 64 + i * 16 + lrow;
    if (m >= M) continue;
#pragma unroll
    for (int j = 0; j < 4; ++j) {
      int colbase = n0 + wn * 64 + j * 16 + kgrp * 4;
      f32x4 v = acc[i][j];
      if (bias) {
        float4 bv4 = *reinterpret_cast<const float4*>(&bias[colbase]);
        v[0] += bv4.x; v[1] += bv4.y; v[2] += bv4.z; v[3] += bv4.w;
      }
      float* cp = &C[(size_t)m * ldc + colbase];
      if (accumulate) {
        float4 o = *reinterpret_cast<const float4*>(cp);
        v[0] += o.x; v[1] += o.y; v[2] += o.z; v[3] += o.w;
      }
      *reinterpret_cast<f32x4*>(cp) = v;
    }
  }
}

// ---------------- GRU elementwise (fp32 state) ----------------
// xw: [N][768] fp32 preacts [r|u|c]; u=sigmoid written back in place; rh -> fp32
__global__ void eltwise_ru(float* __restrict__ xw, const float* __restrict__ h,
                           float* __restrict__ rh) {
  int idx = blockIdx.x * blockDim.x + threadIdx.x;
  if (idx >= NN * 64) return;
  int nrow = idx >> 6;
  int j4 = (idx & 63) << 2;
  float* p = xw + (size_t)nrow * 768 + j4;
  float4 rpre = *reinterpret_cast<const float4*>(p);
  float4 upre = *reinterpret_cast<const float4*>(p + 256);
  float4 hv = *reinterpret_cast<const float4*>(h + (size_t)nrow * 256 + j4);
  float4 uu, rhv;
  uu.x = sigmoidf_(upre.x); uu.y = sigmoidf_(upre.y);
  uu.z = sigmoidf_(upre.z); uu.w = sigmoidf_(upre.w);
  rhv.x = sigmoidf_(rpre.x) * hv.x;
  rhv.y = sigmoidf_(rpre.y) * hv.y;
  rhv.z = sigmoidf_(rpre.z) * hv.z;
  rhv.w = sigmoidf_(rpre.w) * hv.w;
  *reinterpret_cast<float4*>(p + 256) = uu;
  *reinterpret_cast<float4*>(rh + (size_t)nrow * 256 + j4) = rhv;
}

// h fp32 updated in place; optional single-fp16 mirror (for output projection A)
__global__ void eltwise_c(const float* __restrict__ xw, float* __restrict__ h,
                          _Float16* __restrict__ hf) {
  int idx = blockIdx.x * blockDim.x + threadIdx.x;
  if (idx >= NN * 64) return;
  int nrow = idx >> 6;
  int j4 = (idx & 63) << 2;
  float4 cpre = *reinterpret_cast<const float4*>(xw + (size_t)nrow * 768 + 512 + j4);
  float4 uu = *reinterpret_cast<const float4*>(xw + (size_t)nrow * 768 + 256 + j4);
  float* hp = h + (size_t)nrow * 256 + j4;
  float4 hv = *reinterpret_cast<const float4*>(hp);
  float4 nh;
  nh.x = uu.x * hv.x + (1.f - uu.x) * tanhf(cpre.x);
  nh.y = uu.y * hv.y + (1.f - uu.y) * tanhf(cpre.y);
  nh.z = uu.z * hv.z + (1.f - uu.z) * tanhf(cpre.z);
  nh.w = uu.w * hv.w + (1.f - uu.w) * tanhf(cpre.w);
  *reinterpret_cast<float4*>(hp) = nh;
  if (hf) {
    ushort4 hv16;
    hv16.x = f2h(nh.x); hv16.y = f2h(nh.y); hv16.z = f2h(nh.z); hv16.w = f2h(nh.w);
    *reinterpret_cast<ushort4*>(hf + (size_t)nrow * 256 + j4) = hv16;
  }
}

// ---------------- weight prep ----------------
// dst[n][koff+k] = fp16(W[k*ldw + n])
__global__ void wtrans(const float* __restrict__ W, _Float16* __restrict__ dst,
                       int K, int ldw, int ldd, int koff) {
  int k = blockIdx.x * blockDim.x + threadIdx.x;
  int n = blockIdx.y;
  if (k < K) dst[(size_t)n * ldd + koff + k] = (_Float16)W[(size_t)k * ldw + n];
}

__global__ void bias_comb(const float* __restrict__ bx, const float* __restrict__ bh,
                          float* __restrict__ out) {
  int i = blockIdx.x * blockDim.x + threadIdx.x;
  if (i < 768) out[i] = bx[i] + bh[i];
}

__global__ void copy_kernel(const float* __restrict__ in, float* __restrict__ out, int n4) {
  int i = blockIdx.x * blockDim.x + threadIdx.x;
  if (i < n4) reinterpret_cast<float4*>(out)[i] = reinterpret_cast<const float4*>(in)[i];
}

__global__ void cvt16(const float* __restrict__ in, _Float16* __restrict__ out, int n4) {
  int i = blockIdx.x * blockDim.x + threadIdx.x;
  if (i >= n4) return;
  float4 v = reinterpret_cast<const float4*>(in)[i];
  ushort4 o;
  o.x = f2h(v.x); o.y = f2h(v.y); o.z = f2h(v.z); o.w = f2h(v.w);
  reinterpret_cast<ushort4*>(out)[i] = o;
}

// ---------------- host ----------------
extern "C" void kernel_launch(void* const* d_in, const int* in_sizes, int n_in,
                              void* d_out, int out_size, void* d_ws, size_t ws_size,
                              hipStream_t stream) {
  const float* x   = (const float*)d_in[0];
  const float* h0  = (const float*)d_in[1];
  const int*   src = (const int*)d_in[2];
  const int*   dst = (const int*)d_in[3];
  const float* Wx0 = (const float*)d_in[4];
  const float* bx0 = (const float*)d_in[5];
  const float* Wh0 = (const float*)d_in[6];
  const float* bh0 = (const float*)d_in[7];
  const float* Wx1 = (const float*)d_in[8];
  const float* bx1 = (const float*)d_in[9];
  const float* Wh1 = (const float*)d_in[10];
  const float* bh1 = (const float*)d_in[11];
  const float* Wo  = (const float*)d_in[12];
  const float* bo  = (const float*)d_in[13];
  float* out = (float*)d_out;

  char* p = (char*)d_ws;
  auto alloc = [&](size_t bytes) {
    char* r = p;
    p += (bytes + 255) & ~(size_t)255;
    return r;
  };
  int* offs   = (int*)alloc((NN + 1) * sizeof(int));
  int* cursor = (int*)alloc(NN * sizeof(int));
  int* counts = (int*)alloc(NN * sizeof(int));
  int* esrc   = (int*)alloc(NE * sizeof(int));
  // B panels [N][K] fp16: weights duplicated across the hi/lo act K-segments
  _Float16* B0  = (_Float16*)alloc((size_t)768 * 768 * 2);   // k: [Wx|Wx|Wh|Wh], c-row h-part 0
  _Float16* B0h = (_Float16*)alloc((size_t)256 * 512 * 2);   // k: [Whc|Whc]
  _Float16* B1  = (_Float16*)alloc((size_t)768 * 1024 * 2);  // k: [Wx1|Wx1|Wh1|Wh1]
  _Float16* B1h = (_Float16*)alloc((size_t)256 * 512 * 2);
  _Float16* Bo  = (_Float16*)alloc((size_t)128 * 256 * 2);   // single
  float* b0c  = (float*)alloc(768 * 4);
  float* b1c  = (float*)alloc(768 * 4);
  // aggregation outputs: fp16 hi/lo pairs
  _Float16* XAGG  = (_Float16*)alloc((size_t)T_STEPS * NN * 256 * 2);  // [hi128|lo128] per t
  _Float16* H0AGG = (_Float16*)alloc((size_t)NN * 512 * 2);            // [hi256|lo256]
  _Float16* H1AGG = (_Float16*)alloc((size_t)NN * 512 * 2);
  _Float16* RHAGG = (_Float16*)alloc((size_t)NN * 512 * 2);
  _Float16* h1f   = (_Float16*)alloc((size_t)NN * 256 * 2);  // outproj A
  float* rhf  = (float*)alloc((size_t)NN * 256 * 4);
  float* xw   = (float*)alloc((size_t)NN * 768 * 4);

  // fp32 GRU states live directly in d_out tail
  float* h0c = out + (size_t)T_STEPS * NN * FOUT;
  float* h1c = h0c + (size_t)NN * HD;

  // CSR
  hipMemsetAsync(counts, 0, NN * sizeof(int), stream);
  count_kernel<<<(NE + 255) / 256, 256, 0, stream>>>(dst, counts);
  scan_kernel<<<1, 1024, 0, stream>>>(counts, offs, cursor);
  fill_kernel<<<(NE + 255) / 256, 256, 0, stream>>>(src, dst, cursor, esrc);

  // weight prep. c-gate rows of B0/B1 keep an all-zero h-part (c-gate h term
  // arrives via the B0h/B1h accumulate-GEMM) -> memset first.
  hipMemsetAsync(B0, 0, (size_t)768 * 768 * 2, stream);
  hipMemsetAsync(B1, 0, (size_t)768 * 1024 * 2, stream);
  for (int g = 0; g < 3; ++g) {
    const float* W = Wx0 + (size_t)g * 128 * 256;
    _Float16* D = B0 + (size_t)g * 256 * 768;
    wtrans<<<dim3(1, 256), 256, 0, stream>>>(W, D, 128, 256, 768, 0);
    wtrans<<<dim3(1, 256), 256, 0, stream>>>(W, D, 128, 256, 768, 128);
  }
  for (int g = 0; g < 2; ++g) {
    const float* W = Wh0 + (size_t)g * 256 * 256;
    _Float16* D = B0 + (size_t)g * 256 * 768;
    wtrans<<<dim3(1, 256), 256, 0, stream>>>(W, D, 256, 256, 768, 256);
    wtrans<<<dim3(1, 256), 256, 0, stream>>>(W, D, 256, 256, 768, 512);
  }
  wtrans<<<dim3(1, 256), 256, 0, stream>>>(Wh0 + (size_t)2 * 256 * 256, B0h, 256, 256, 512, 0);
  wtrans<<<dim3(1, 256), 256, 0, stream>>>(Wh0 + (size_t)2 * 256 * 256, B0h, 256, 256, 512, 256);
  for (int g = 0; g < 3; ++g) {
    const float* W = Wx1 + (size_t)g * 256 * 256;
    _Float16* D = B1 + (size_t)g * 256 * 1024;
    wtrans<<<dim3(1, 256), 256, 0, stream>>>(W, D, 256, 256, 1024, 0);
    wtrans<<<dim3(1, 256), 256, 0, stream>>>(W, D, 256, 256, 1024, 256);
  }
  for (int g = 0; g < 2; ++g) {
    const float* W = Wh1 + (size_t)g * 256 * 256;
    _Float16* D = B1 + (size_t)g * 256 * 1024;
    wtrans<<<dim3(1, 256), 256, 0, stream>>>(W, D, 256, 256, 1024, 512);
    wtrans<<<dim3(1, 256), 256, 0, stream>>>(W, D, 256, 256, 1024, 768);
  }
  wtrans<<<dim3(1, 256), 256, 0, stream>>>(Wh1 + (size_t)2 * 256 * 256, B1h, 256, 256, 512, 0);
  wtrans<<<dim3(1, 256), 256, 0, stream>>>(Wh1 + (size_t)2 * 256 * 256, B1h, 256, 256, 512, 256);
  wtrans<<<dim3(1, 128), 256, 0, stream>>>(Wo, Bo, 256, 128, 256, 0);
  bias_comb<<<3, 256, 0, stream>>>(bx0, bh0, b0c);
  bias_comb<<<3, 256, 0, stream>>>(bx1, bh1, b1c);

  // init states: fp32 in out tail; h1f mirror for t=0 outproj comes from eltwise_c later
  copy_kernel<<<(2 * NN * HD / 4 + 255) / 256, 256, 0, stream>>>(h0, h0c, 2 * NN * HD / 4);

  dim3 blk(256);
  const int RPG = 20;  // ceil(157 row-tiles / 8 XCDs)
  int g6 = 8 * RPG * 6, g2 = 8 * RPG * 2, g1 = 8 * RPG * 1;
  int ew_blocks = (NN * 64 + 255) / 256;
  int agg_grid = NN / 4;

  // all-t x aggregation in one batched launch (fp32 src -> hi/lo fp16)
  agg_split_x<<<dim3(agg_grid, T_STEPS), blk, 0, stream>>>(x, offs, esrc, XAGG);
  // prime H0AGG = agg(h0_init)
  agg_split<HD><<<agg_grid, blk, 0, stream>>>(h0c, offs, esrc, H0AGG, 512);

  for (int t = 0; t < T_STEPS; ++t) {
    // H1AGG = agg(h1_{t-1}) — independent of layer 0
    agg_split<HD><<<agg_grid, blk, 0, stream>>>(h1c, offs, esrc, H1AGG, 512);

    // ---- layer 0 ----  A = [xagg hi|lo (256) | h0agg hi|lo (512)], K=768
    gemm_f16<<<g6, blk, 0, stream>>>(XAGG + (size_t)t * NN * 256, 256, 256,
                                     H0AGG, 512, B0, 768, xw, 768, b0c, NN, 768, 0, 6, RPG);
    eltwise_ru<<<ew_blocks, blk, 0, stream>>>(xw, h0c, rhf);
    agg_split<HD><<<agg_grid, blk, 0, stream>>>(rhf, offs, esrc, RHAGG, 512);
    gemm_f16<<<g2, blk, 0, stream>>>(RHAGG, 512, 512, nullptr, 0, B0h, 512,
                                     xw + 512, 768, nullptr, NN, 512, 1, 2, RPG);
    eltwise_c<<<ew_blocks, blk, 0, stream>>>(xw, h0c, nullptr);
    agg_split<HD><<<agg_grid, blk, 0, stream>>>(h0c, offs, esrc, H0AGG, 512);  // agg(h0_t)

    // ---- layer 1 ----  A = [h0agg (512) | h1agg (512)], K=1024
    gemm_f16<<<g6, blk, 0, stream>>>(H0AGG, 512, 512, H1AGG, 512, B1, 1024,
                                     xw, 768, b1c, NN, 1024, 0, 6, RPG);
    eltwise_ru<<<ew_blocks, blk, 0, stream>>>(xw, h1c, rhf);
    agg_split<HD><<<agg_grid, blk, 0, stream>>>(rhf, offs, esrc, RHAGG, 512);
    gemm_f16<<<g2, blk, 0, stream>>>(RHAGG, 512, 512, nullptr, 0, B1h, 512,
                                     xw + 512, 768, nullptr, NN, 512, 1, 2, RPG);
    eltwise_c<<<ew_blocks, blk, 0, stream>>>(xw, h1c, h1f);

    // ---- output projection ----  A = h1f (fp16 mirror), K=256
    gemm_f16<<<g1, blk, 0, stream>>>(h1f, 256, 256, nullptr, 0, Bo, 256,
                                     out + (size_t)t * NN * FOUT, FOUT, bo,
                                     NN, 256, 0, 1, RPG);
  }
}